// Round 1
// baseline (208.047 us; speedup 1.0000x reference)
//
#include <hip/hip_runtime.h>
#include <math.h>

// Problem constants
#define TT 8
#define BB 128
#define GDIM 16
#define GG 256
#define DD 64
#define SQ 17   // float4s per cell row in LDS (68 floats, odd*4 => conflict-free b128)

// ws accumulator layout (floats):
// [0] z_what_loss  [1] z_pres_loss  [2] pool (signed, already negated)
// [3] objects      [4] flow masked sq [5] sum(zp) [6] sum(flow)

__device__ inline float wred(float v) {
#pragma unroll
    for (int off = 32; off > 0; off >>= 1) v += __shfl_xor(v, off, 64);
    return v;
}

__global__ __launch_bounds__(256) void pair_kernel(const float* __restrict__ zw,
                                                   const float* __restrict__ zp,
                                                   float* __restrict__ acc) {
    const int pairIdx = blockIdx.x;           // 0 .. 7*BB-1
    const int t = pairIdx / BB;
    const int b = pairIdx - t * BB;
    const int tid = threadIdx.x;

    __shared__ float4 shA4[GG * SQ];          // z_what[t]   tile, padded
    __shared__ float4 shB4[GG * SQ];          // z_what[t+1] tile, padded
    __shared__ float pA[GG], pB[GG], nA[GG], nB[GG];
    __shared__ float bred[3][4];

    const float4* gA = (const float4*)(zw + (size_t)(t * BB + b) * (GG * DD));
    const float4* gB = (const float4*)(zw + (size_t)((t + 1) * BB + b) * (GG * DD));

    // ---- load both tiles + adjacent-diff loss in-flight ----
    float zdiff = 0.f;
#pragma unroll
    for (int k = 0; k < 16; k++) {
        int i = tid + k * 256;                // float4 index 0..4095
        float4 a = gA[i];
        float4 bb4 = gB[i];
        float dx = bb4.x - a.x, dy = bb4.y - a.y, dz = bb4.z - a.z, dw = bb4.w - a.w;
        zdiff += dx * dx + dy * dy + dz * dz + dw * dw;
        int cell = i >> 4;
        int c = i & 15;
        shA4[cell * SQ + c] = a;
        shB4[cell * SQ + c] = bb4;
    }
    pA[tid] = zp[(size_t)(t * BB + b) * GG + tid];
    pB[tid] = zp[(size_t)((t + 1) * BB + b) * GG + tid];
    __syncthreads();

    // ---- pre-pass: per-cell norms (thread = cell) ----
    {
        float sa = 0.f, sb = 0.f;
#pragma unroll
        for (int q = 0; q < 16; q++) {
            float4 a = shA4[tid * SQ + q];
            float4 bb4 = shB4[tid * SQ + q];
            sa += a.x * a.x + a.y * a.y + a.z * a.z + a.w * a.w;
            sb += bb4.x * bb4.x + bb4.y * bb4.y + bb4.z * bb4.z + bb4.w * bb4.w;
        }
        nA[tid] = sqrtf(sa);
        nB[tid] = sqrtf(sb);
    }
    __syncthreads();

    // ---- main pass: thread = cell ----
    const int gi = tid >> 4, gj = tid & 15;

    int nbc[9];
    float papool[9];
    float nbn[9];
    unsigned nbpM = 0;
    {
        int m = 0;
#pragma unroll
        for (int di = -1; di <= 1; di++) {
#pragma unroll
            for (int dj = -1; dj <= 1; dj++) {
                int iw = (gi + di) & 15, jw = (gj + dj) & 15;
                int c = (iw << 4) | jw;
                nbc[m] = c;
                bool inb = ((unsigned)(gi + di) < 16u) && ((unsigned)(gj + dj) < 16u);
                papool[m] = inb ? pA[c] : 0.f;    // OOB contributes 0 (safe: all cands >= 0)
                nbn[m] = fmaxf(nB[c], 1e-8f);
                if (pB[c] > 0.5f) nbpM |= (1u << m);
                m++;
            }
        }
    }

    float dots[9] = {0.f, 0.f, 0.f, 0.f, 0.f, 0.f, 0.f, 0.f, 0.f};
    float poolDot = 0.f, poolN = 0.f;

#pragma unroll 2
    for (int q = 0; q < 16; q++) {
        float4 a = shA4[tid * SQ + q];
        float4 bc = shB4[tid * SQ + q];
        dots[4] += a.x * bc.x + a.y * bc.y + a.z * bc.z + a.w * bc.w;
        float smx = papool[4] * fabsf(a.x);
        float smy = papool[4] * fabsf(a.y);
        float smz = papool[4] * fabsf(a.z);
        float smw = papool[4] * fabsf(a.w);
#pragma unroll
        for (int k = 0; k < 9; k++) {
            if (k == 4) continue;
            float4 an = shA4[nbc[k] * SQ + q];
            float4 bn = shB4[nbc[k] * SQ + q];
            dots[k] += a.x * bn.x + a.y * bn.y + a.z * bn.z + a.w * bn.w;
            smx = fmaxf(smx, papool[k] * fabsf(an.x));
            smy = fmaxf(smy, papool[k] * fabsf(an.y));
            smz = fmaxf(smz, papool[k] * fabsf(an.z));
            smw = fmaxf(smw, papool[k] * fabsf(an.w));
        }
        poolDot += smx * fabsf(bc.x) + smy * fabsf(bc.y) + smz * fabsf(bc.z) + smw * fabsf(bc.w);
        poolN += smx * smx + smy * smy + smz * smz + smw * smw;
    }

    // objects epilogue
    float prior_n = fmaxf(nA[tid], 1e-8f);
    float sum_sim = 0.f, max_sim = -1e30f;
    bool has = false;
#pragma unroll
    for (int k = 0; k < 9; k++) {
        float s = dots[k] / (prior_n * nbn[k]);
        if ((nbpM >> k) & 1u) {
            sum_sim += s;
            max_sim = fmaxf(max_sim, s);
            has = true;
        }
    }
    float obj = ((pA[tid] > 0.5f) && has) ? (sum_sim - 5.0f * max_sim) : 0.f;

    // pool epilogue:  dot = pB * poolDot ; ||wB|| = pB * nB ; na = ||smoothed||
    float na_pool = fmaxf(sqrtf(poolN), 1e-6f);
    float nb_pool = fmaxf(pB[tid] * nB[tid], 1e-6f);
    float cosp = (pB[tid] * poolDot) / (na_pool * nb_pool);
    float poolc = -cosp * 0.5f * (pA[tid] + pB[tid]);

    // ---- block reduce 3 scalars ----
    float r0 = wred(zdiff);
    float r1 = wred(obj);
    float r2 = wred(poolc);
    int w = tid >> 6;
    if ((tid & 63) == 0) {
        bred[0][w] = r0;
        bred[1][w] = r1;
        bred[2][w] = r2;
    }
    __syncthreads();
    if (tid == 0) {
        atomicAdd(&acc[0], bred[0][0] + bred[0][1] + bred[0][2] + bred[0][3]);
        atomicAdd(&acc[3], bred[1][0] + bred[1][1] + bred[1][2] + bred[1][3]);
        atomicAdd(&acc[2], bred[2][0] + bred[2][1] + bred[2][2] + bred[2][3]);
    }
}

__global__ __launch_bounds__(256) void presflow_kernel(const float* __restrict__ zp,
                                                       const float* __restrict__ flow,
                                                       float* __restrict__ acc) {
    const int tb = blockIdx.x;                // 0 .. TT*BB-1, t-major
    const int tid = threadIdx.x;
    __shared__ float p[GG];
    __shared__ float bred[4][4];

    p[tid] = zp[(size_t)tb * GG + tid];
    float f = flow[(size_t)tb * GG + tid];
    __syncthreads();

    const int gi = tid >> 4, gj = tid & 15;
    float mx = -1e30f;
#pragma unroll
    for (int di = -1; di <= 1; di++) {
        int ii = gi + di;
        if ((unsigned)ii >= 16u) continue;
#pragma unroll
        for (int dj = -1; dj <= 1; dj++) {
            int jj = gj + dj;
            if ((unsigned)jj >= 16u) continue;
            mx = fmaxf(mx, p[(ii << 4) | jj]);
        }
    }
    float flow_sq = 0.f;
    if (f > 0.5f) {
        float d = mx - f;
        flow_sq = d * d;
    }
    float szp = p[tid];
    float sflow = f;

    float pres = 0.f;
    int t = tb / BB;
    if (t <= TT - 3) {
        float p0 = p[tid];
        float p1 = zp[(size_t)(tb + BB) * GG + tid];
        float p2 = zp[(size_t)(tb + 2 * BB) * GG + tid];
        float sim = 1.f - (p2 - p0) * (p2 - p0);
        float dl = (p2 - p1) * (p2 - p1) + (p0 - p1) * (p0 - p1);
        pres = sim * dl;
    }

    float r0 = wred(pres);
    float r1 = wred(flow_sq);
    float r2 = wred(szp);
    float r3 = wred(sflow);
    int w = tid >> 6;
    if ((tid & 63) == 0) {
        bred[0][w] = r0;
        bred[1][w] = r1;
        bred[2][w] = r2;
        bred[3][w] = r3;
    }
    __syncthreads();
    if (tid == 0) {
        atomicAdd(&acc[1], bred[0][0] + bred[0][1] + bred[0][2] + bred[0][3]);
        atomicAdd(&acc[4], bred[1][0] + bred[1][1] + bred[1][2] + bred[1][3]);
        atomicAdd(&acc[5], bred[2][0] + bred[2][1] + bred[2][2] + bred[2][3]);
        atomicAdd(&acc[6], bred[3][0] + bred[3][1] + bred[3][2] + bred[3][3]);
    }
}

__global__ void final_kernel(const float* __restrict__ acc, const int* __restrict__ gs,
                             float* __restrict__ out) {
    if (threadIdx.x == 0 && blockIdx.x == 0) {
        float step = (float)gs[0];
        float scale_obj = fminf(1.f, step / 200000.f);
        float scale_flow = fmaxf(0.f, 1.f - step / 100000.f);
        float flow_loss = acc[4] + 100.f * fmaxf(0.f, acc[5] - acc[6]);
        out[0] = acc[0] * 1.0f            // z_what_loss * ADJ_W
               + acc[1] * 1.0f            // z_pres_loss * PRES_W
               + acc[2] * 1.0f            // pool (already negated) * POOL_W
               + acc[3] * scale_obj * 10.0f
               + flow_loss * 1.0f * scale_flow;
    }
}

extern "C" void kernel_launch(void* const* d_in, const int* in_sizes, int n_in,
                              void* d_out, int out_size, void* d_ws, size_t ws_size,
                              hipStream_t stream) {
    const float* zw = (const float*)d_in[0];
    const float* zp = (const float*)d_in[1];
    const float* fl = (const float*)d_in[2];
    const int* gs = (const int*)d_in[3];
    float* acc = (float*)d_ws;

    hipMemsetAsync(d_ws, 0, 8 * sizeof(float), stream);
    pair_kernel<<<(TT - 1) * BB, 256, 0, stream>>>(zw, zp, acc);
    presflow_kernel<<<TT * BB, 256, 0, stream>>>(zp, fl, acc);
    final_kernel<<<1, 64, 0, stream>>>(acc, gs, (float*)d_out);
}